// Round 6
// baseline (234.953 us; speedup 1.0000x reference)
//
#include <hip/hip_runtime.h>
#include <math.h>

typedef __bf16 bf16x8 __attribute__((ext_vector_type(8)));
typedef float f32x4 __attribute__((ext_vector_type(4)));

namespace {
constexpr int DIMC = 1024, NH = 16, HD = 64, SEQ = 2048;
constexpr float SCL = 0.125f;  // 1/(tau*sqrt(64))
}

__device__ __forceinline__ unsigned short f2b(float f) {
  unsigned u = __float_as_uint(f);
  return (unsigned short)((u + 0x7fffu + ((u >> 16) & 1u)) >> 16);
}
__device__ __forceinline__ float b2f(unsigned short s) {
  return __uint_as_float((unsigned)s << 16);
}
__device__ __forceinline__ unsigned cvtpk(float lo, float hi) {
  unsigned r;
  asm("v_cvt_pk_bf16_f32 %0, %1, %2" : "=v"(r) : "v"(lo), "v"(hi));
  return r;
}

// fp32 -> bf16 (RNE), 8 elements per thread
__global__ __launch_bounds__(256)
void cvt_bf16(const float* __restrict__ in, unsigned short* __restrict__ out, int n8) {
  int i = blockIdx.x * 256 + threadIdx.x;
  if (i >= n8) return;
  const float4* in4 = (const float4*)in;
  float4 a = in4[2 * i], b = in4[2 * i + 1];
  union { unsigned short u[8]; uint4 v; } r;
  r.u[0] = f2b(a.x); r.u[1] = f2b(a.y); r.u[2] = f2b(a.z); r.u[3] = f2b(a.w);
  r.u[4] = f2b(b.x); r.u[5] = f2b(b.y); r.u[6] = f2b(b.z); r.u[7] = f2b(b.w);
  ((uint4*)out)[i] = r.v;
}

// all 4 weight matrices in one launch; outputs contiguous
__global__ __launch_bounds__(256)
void cvt_w4(const float* __restrict__ w0, const float* __restrict__ w1,
            const float* __restrict__ w2, const float* __restrict__ w3,
            unsigned short* __restrict__ out) {
  const int which = blockIdx.y;
  const float* src = which == 0 ? w0 : which == 1 ? w1 : which == 2 ? w2 : w3;
  unsigned short* dst = out + (size_t)which * 1048576;
  int i = blockIdx.x * 256 + threadIdx.x;
  const float4* in4 = (const float4*)src;
  float4 a = in4[2 * i], b = in4[2 * i + 1];
  union { unsigned short u[8]; uint4 v; } r;
  r.u[0] = f2b(a.x); r.u[1] = f2b(a.y); r.u[2] = f2b(a.z); r.u[3] = f2b(a.w);
  r.u[4] = f2b(b.x); r.u[5] = f2b(b.y); r.u[6] = f2b(b.z); r.u[7] = f2b(b.w);
  ((uint4*)dst)[i] = r.v;
}

// ---- shared GEMM tile body (round-2 proven, reg-staged) ----
template<int MODE>
__device__ __forceinline__
void gemm_tile(const unsigned short* __restrict__ A, const unsigned short* __restrict__ W,
               const float* __restrict__ bias, void* __restrict__ Cout,
               int bm, int bn, char* As, char* Bs) {
  const int tid = threadIdx.x, lane = tid & 63, w = tid >> 6;
  const int p = lane & 15, g = lane >> 4;
  const int wr = w >> 1, wc = w & 1;
  const int sr = tid >> 2, sc = (tid & 3) * 8;

  f32x4 acc[4][2];
#pragma unroll
  for (int mf = 0; mf < 4; ++mf)
#pragma unroll
    for (int nf = 0; nf < 2; ++nf)
      acc[mf][nf] = (f32x4){0.f, 0.f, 0.f, 0.f};

  const size_t arow0 = (size_t)(bm + sr) * DIMC + sc;
  const size_t arow1 = (size_t)(bm + 64 + sr) * DIMC + sc;
  const size_t brow  = (size_t)(bn + sr) * DIMC + sc;

  for (int k0 = 0; k0 < DIMC; k0 += 32) {
    const bf16x8 va0 = *(const bf16x8*)&A[arow0 + k0];
    const bf16x8 va1 = *(const bf16x8*)&A[arow1 + k0];
    const bf16x8 vb  = *(const bf16x8*)&W[brow + k0];
    __syncthreads();
    *(bf16x8*)&As[tid * 16] = va0;
    *(bf16x8*)&As[4096 + tid * 16] = va1;
    *(bf16x8*)&Bs[tid * 16] = vb;
    __syncthreads();
    bf16x8 af[4], bfr[2];
#pragma unroll
    for (int mf = 0; mf < 4; ++mf)
      af[mf] = *(const bf16x8*)&As[(wr * 64 + mf * 16 + p) * 64 + g * 16];
#pragma unroll
    for (int nf = 0; nf < 2; ++nf)
      bfr[nf] = *(const bf16x8*)&Bs[(wc * 32 + nf * 16 + p) * 64 + g * 16];
#pragma unroll
    for (int mf = 0; mf < 4; ++mf)
#pragma unroll
      for (int nf = 0; nf < 2; ++nf)
        acc[mf][nf] = __builtin_amdgcn_mfma_f32_16x16x32_bf16(af[mf], bfr[nf], acc[mf][nf], 0, 0, 0);
  }

#pragma unroll
  for (int nf = 0; nf < 2; ++nf) {
    const int cg = bn + wc * 32 + nf * 16 + p;
    const float bv = bias[cg & (DIMC - 1)];
#pragma unroll
    for (int mf = 0; mf < 4; ++mf) {
#pragma unroll
      for (int j = 0; j < 4; ++j) {
        const int rg = bm + wr * 64 + mf * 16 + g * 4 + j;
        const float v = acc[mf][nf][j] + bv;
        if (MODE == 0) {
          ((float*)Cout)[(size_t)rg * DIMC + cg] = v;
        } else {
          const int bb = rg >> 11, ss = rg & (SEQ - 1);
          const int hh = cg >> 6, dd = cg & (HD - 1);
          ((unsigned short*)Cout)[(((size_t)(bb * NH + hh) * SEQ + ss) * HD) + dd] = f2b(v);
        }
      }
    }
  }
}

__global__ __launch_bounds__(256, 2)
void gemm_out(const unsigned short* __restrict__ A, const unsigned short* __restrict__ W,
              const float* __restrict__ bias, float* __restrict__ Cout) {
  __shared__ char As[8192];
  __shared__ char Bs[4096];
  gemm_tile<0>(A, W, bias, Cout, blockIdx.x * 128, blockIdx.y * 64, As, Bs);
}

__global__ __launch_bounds__(256, 2)
void gemm_qkv(const unsigned short* __restrict__ A, const unsigned short* __restrict__ Wall,
              const float* __restrict__ bq, const float* __restrict__ bk,
              const float* __restrict__ bv, unsigned short* __restrict__ Out) {
  __shared__ char As[8192];
  __shared__ char Bs[4096];
  const int which = blockIdx.y >> 4;
  const unsigned short* W = Wall + (size_t)which * 1048576;
  const float* bias = which == 0 ? bq : which == 1 ? bk : bv;
  unsigned short* Cout = Out + (size_t)which * 4194304;
  gemm_tile<1>(A, W, bias, Cout, blockIdx.x * 128, (blockIdx.y & 15) * 64, As, Bs);
}

// Flash attention, swapped-operand MFMA, 64 q-rows/block (16/wave), 4 blocks/CU.
// grid: x = bh (32) -> XCD = bh%8 (head-local L2), y = q-tile (32).
__global__ __launch_bounds__(256, 4)
void attn_mfma(const unsigned short* __restrict__ Q, const unsigned short* __restrict__ K,
               const unsigned short* __restrict__ V, unsigned short* __restrict__ Y) {
  __shared__ char Vt[2][8192];  // V^T [64 d][64 key] bf16, XOR-swizzled, dbuf
  __shared__ char Pl[2][8192];  // P [64 q][64 key] bf16, XOR-swizzled, dbuf
  const int tid = threadIdx.x, lane = tid & 63, w = tid >> 6;
  const int p = lane & 15, g = lane >> 4;
  const int bh = blockIdx.x, b = bh >> 4, h = bh & 15;
  const int q0 = blockIdx.y * 64, qw = q0 + w * 16;
  const size_t base = (size_t)bh * SEQ * HD;
  const unsigned short* Qp = Q + base;
  const unsigned short* Kp = K + base;
  const unsigned short* Vp = V + base;

  // Q fragments: B-operand (col=q). lane(p,g): q=qw+p, k(d)=ks*32+g*8+j
  bf16x8 qf[2];
#pragma unroll
  for (int ks = 0; ks < 2; ++ks)
    qf[ks] = *(const bf16x8*)&Qp[(size_t)(qw + p) * HD + ks * 32 + g * 8];

  f32x4 o2[4];   // O^T frags: col q = p, row d = nfd*16+g*4+j
#pragma unroll
  for (int nf = 0; nf < 4; ++nf)
    o2[nf] = (f32x4){0.f, 0.f, 0.f, 0.f};
  float m2 = -INFINITY, lr = 0.f;

  const int kp = tid & 31, vd0 = (tid >> 5) * 8;  // V-stage mapping

  for (int kt = 0; kt < SEQ / 64; ++kt) {
    const int par = kt & 1;
    const int kb = kt * 64;
    // K fragments: A-operand (row=key). lane(p,g): key=kb+nf*16+p, k(d)=ks*32+g*8+j
    bf16x8 kf[4][2];
#pragma unroll
    for (int nf = 0; nf < 4; ++nf)
#pragma unroll
      for (int ks = 0; ks < 2; ++ks)
        kf[nf][ks] = *(const bf16x8*)&Kp[(size_t)(kb + nf * 16 + p) * HD + ks * 32 + g * 8];
    union { bf16x8 v; unsigned short u[8]; } v0, v1;
    v0.v = *(const bf16x8*)&Vp[(size_t)(kb + 2 * kp) * HD + vd0];
    v1.v = *(const bf16x8*)&Vp[(size_t)(kb + 2 * kp + 1) * HD + vd0];

    // S^T = K Q^T : frag(nf), lane(p,g): S[q=qw+p][key=kb+nf*16+g*4+j]
    f32x4 s2[4];
#pragma unroll
    for (int nf = 0; nf < 4; ++nf)
      s2[nf] = (f32x4){0.f, 0.f, 0.f, 0.f};
    __builtin_amdgcn_s_setprio(1);
#pragma unroll
    for (int nf = 0; nf < 4; ++nf)
#pragma unroll
      for (int ks = 0; ks < 2; ++ks)
        s2[nf] = __builtin_amdgcn_mfma_f32_16x16x32_bf16(kf[nf][ks], qf[ks], s2[nf], 0, 0, 0);
    __builtin_amdgcn_s_setprio(0);

    // lane-local online softmax (q = lane's column) with defer-max (THR=8)
    unsigned pk[8];
    {
      float tm = s2[0][0];
#pragma unroll
      for (int nf = 0; nf < 4; ++nf)
#pragma unroll
        for (int j = 0; j < 4; ++j) tm = fmaxf(tm, s2[nf][j]);
      tm = fmaxf(tm, __shfl_xor(tm, 16));
      tm = fmaxf(tm, __shfl_xor(tm, 32));
      tm *= SCL;
      float nm;
      if (__all(tm - m2 <= 8.0f)) {
        nm = m2;                       // defer: keep old max, no rescale
      } else {
        nm = fmaxf(m2, tm);
        const float rc = __expf(m2 - nm);
        lr *= rc;
#pragma unroll
        for (int nf = 0; nf < 4; ++nf)
#pragma unroll
          for (int j = 0; j < 4; ++j) o2[nf][j] *= rc;
        m2 = nm;
      }
      float rs = 0.f;
#pragma unroll
      for (int nf = 0; nf < 4; ++nf)
#pragma unroll
        for (int j = 0; j < 4; ++j) {
          const float e = __expf(s2[nf][j] * SCL - nm);
          s2[nf][j] = e;
          rs += e;
        }
      rs += __shfl_xor(rs, 16);
      rs += __shfl_xor(rs, 32);
      lr += rs;
#pragma unroll
      for (int nf = 0; nf < 4; ++nf) {
        pk[2 * nf]     = cvtpk(s2[nf][0], s2[nf][1]);
        pk[2 * nf + 1] = cvtpk(s2[nf][2], s2[nf][3]);
      }
    }

    // stage P: row q = w*16+p, cols keys nf*16+g*4+{2t,2t+1} as u32
    {
      const int r = w * 16 + p;
      const int swz = (r & 7) << 4;
#pragma unroll
      for (int nf = 0; nf < 4; ++nf)
#pragma unroll
        for (int t = 0; t < 2; ++t)
          *(unsigned*)&Pl[par][r * 128 + ((nf * 32 + g * 8 + 4 * t) ^ swz)] = pk[2 * nf + t];
    }
    // stage V^T (paired keys -> u32), swizzle byte ^= (d&7)<<4
#pragma unroll
    for (int e = 0; e < 8; ++e) {
      const int d = vd0 + e;
      const unsigned val = (unsigned)v0.u[e] | ((unsigned)v1.u[e] << 16);
      *(unsigned*)&Vt[par][d * 128 + ((kp * 4) ^ ((d & 7) << 4))] = val;
    }
    __syncthreads();

    // O^T += V^T · P^T  (A = V^T rows d; B = P rows q read as cols)
    bf16x8 pf[2], vb[4][2];
    {
      const int r = w * 16 + p;
      const int swz = (r & 7) << 4;
#pragma unroll
      for (int ks = 0; ks < 2; ++ks)
        pf[ks] = *(const bf16x8*)&Pl[par][r * 128 + ((ks * 64 + g * 16) ^ swz)];
    }
#pragma unroll
    for (int nfd = 0; nfd < 4; ++nfd) {
      const int d = nfd * 16 + p;
      const int swz = (d & 7) << 4;
#pragma unroll
      for (int ks = 0; ks < 2; ++ks)
        vb[nfd][ks] = *(const bf16x8*)&Vt[par][d * 128 + ((ks * 64 + g * 16) ^ swz)];
    }
    __builtin_amdgcn_s_setprio(1);
#pragma unroll
    for (int nfd = 0; nfd < 4; ++nfd)
#pragma unroll
      for (int ks = 0; ks < 2; ++ks)
        o2[nfd] = __builtin_amdgcn_mfma_f32_16x16x32_bf16(vb[nfd][ks], pf[ks], o2[nfd], 0, 0, 0);
    __builtin_amdgcn_s_setprio(0);
  }

  // epilogue: out = 0.6*O/l + 0.4*(L@V); q lane-local, d contiguous by 4
  const float e1 = 4.3936934e-2f, e2 = 3.7266532e-6f, e3 = 6.1019804e-13f;
  const float lwv[4] = {1.f, e1, e2, e3};
  {
    const int q = qw + p;
    const float inv = 0.6f / lr;
    float wsum = 0.f;
#pragma unroll
    for (int dd = -3; dd <= 3; ++dd) {
      const int kk = q + dd;
      if (kk >= 0 && kk < SEQ) wsum += lwv[dd < 0 ? -dd : dd];
    }
    const float wn = 0.4f / (wsum + 1e-10f);
#pragma unroll
    for (int nfd = 0; nfd < 4; ++nfd) {
      const int d0 = nfd * 16 + g * 4;
      float loc[4] = {0.f, 0.f, 0.f, 0.f};
#pragma unroll
      for (int dd = -3; dd <= 3; ++dd) {
        const int kk = q + dd;
        if (kk >= 0 && kk < SEQ) {
          const uint2 lv = *(const uint2*)&Vp[(size_t)kk * HD + d0];
          const float wt = lwv[dd < 0 ? -dd : dd];
          loc[0] = fmaf(wt, b2f((unsigned short)lv.x), loc[0]);
          loc[1] = fmaf(wt, b2f((unsigned short)(lv.x >> 16)), loc[1]);
          loc[2] = fmaf(wt, b2f((unsigned short)lv.y), loc[2]);
          loc[3] = fmaf(wt, b2f((unsigned short)(lv.y >> 16)), loc[3]);
        }
      }
      uint2 st;
      st.x = cvtpk(o2[nfd][0] * inv + loc[0] * wn, o2[nfd][1] * inv + loc[1] * wn);
      st.y = cvtpk(o2[nfd][2] * inv + loc[2] * wn, o2[nfd][3] * inv + loc[3] * wn);
      *(uint2*)&Y[((size_t)(b * SEQ + q)) * DIMC + h * HD + d0] = st;
    }
  }
}

extern "C" void kernel_launch(void* const* d_in, const int* in_sizes, int n_in,
                              void* d_out, int out_size, void* d_ws, size_t ws_size,
                              hipStream_t stream) {
  (void)in_sizes; (void)n_in; (void)out_size; (void)ws_size;
  const float* x  = (const float*)d_in[0];
  const float* Wq = (const float*)d_in[1];
  const float* bq = (const float*)d_in[2];
  const float* Wk = (const float*)d_in[3];
  const float* bk = (const float*)d_in[4];
  const float* Wv = (const float*)d_in[5];
  const float* bv = (const float*)d_in[6];
  const float* Wo = (const float*)d_in[7];
  const float* bo = (const float*)d_in[8];

  char* ws = (char*)d_ws;
  unsigned short* xb  = (unsigned short*)(ws);               // 8 MB
  unsigned short* Wqb = (unsigned short*)(ws + 8388608);     // 2 MB each, contiguous (Wq,Wk,Wv,Wo)
  unsigned short* Wob = (unsigned short*)(ws + 14680064);
  unsigned short* Qh  = (unsigned short*)(ws + 16777216);    // 8 MB each, contiguous (Q,K,V)
  unsigned short* Kh  = (unsigned short*)(ws + 25165824);
  unsigned short* Vh  = (unsigned short*)(ws + 33554432);
  unsigned short* Yb  = (unsigned short*)(ws + 41943040);

  dim3 blk(256);
  cvt_bf16<<<2048, blk, 0, stream>>>(x, xb, 524288);
  cvt_w4<<<dim3(512, 4), blk, 0, stream>>>(Wq, Wk, Wv, Wo, Wqb);

  gemm_qkv<<<dim3(32, 48), blk, 0, stream>>>(xb, Wqb, bq, bk, bv, Qh);

  attn_mfma<<<dim3(32, 32), blk, 0, stream>>>(Qh, Kh, Vh, Yb);

  gemm_out<<<dim3(32, 16), blk, 0, stream>>>(Yb, Wob, bo, (float*)d_out);
}